// Round 8
// baseline (1395.901 us; speedup 1.0000x reference)
//
#include <hip/hip_runtime.h>

// Viterbi decode (CRF): B=128, T=4096, L=64.
// Outputs: score[B] (f32), path[B][T] (written as float labels).
constexpr int kB = 128;
constexpr int kT = 4096;
constexpr int kL = 64;
constexpr int kSeg = 64;     // number of backtrace segments
constexpr int kSegLen = 64;  // rows per segment (last segment has 63)
constexpr float kNeg = -10000.0f;

typedef float f32x2 __attribute__((ext_vector_type(2)));
typedef float f32x4 __attribute__((ext_vector_type(4)));

// ---------------- K1A forward: all-VALU broadcast via permlane+DPP ----------
// Lane i owns label i; delta in ONE register. Broadcast:
//   (a,b) = v_permlane32_swap(d,d); sa,sb = ds_swizzle xor-16 of a,b.
// Per 16-lane row, the 4 bases hold 4 distinct 16-label chunks; 15 DPP
// row_ror adds + 1 plain add per base cover the chunk. Transition values are
// gathered at init in PROBED order (run the pipeline on lane indices), so no
// assumption about permlane/ror semantics is needed. s_nop 1 before the first
// DPP read of each base guards the VALU-write->DPP-read hazard (2 wait
// states, NOT inserted by the compiler around inline asm).

#define ADD_ROR(dst, base, trv, K)                                              \
  asm("v_add_f32_dpp %0, %1, %2 row_ror:" #K " row_mask:0xf bank_mask:0xf"      \
      : "=v"(dst)                                                               \
      : "v"(base), "v"(trv))

#define ADD_ROR_FIRST(dst, base, trv, K)                                        \
  asm("s_nop 1\n\tv_add_f32_dpp %0, %1, %2 row_ror:" #K                         \
      " row_mask:0xf bank_mask:0xf"                                             \
      : "=v"(dst)                                                               \
      : "v"(base), "v"(trv))

__device__ __forceinline__ float reduce16(float base, const float (&tr)[16]) {
  float t0, t1, t2, t3, t4, t5, t6, t7, t8, t9, t10, t11, t12, t13, t14, t15;
  t0 = base + tr[0];
  ADD_ROR_FIRST(t1, base, tr[1], 1);
  ADD_ROR(t2, base, tr[2], 2);
  ADD_ROR(t3, base, tr[3], 3);
  ADD_ROR(t4, base, tr[4], 4);
  ADD_ROR(t5, base, tr[5], 5);
  ADD_ROR(t6, base, tr[6], 6);
  ADD_ROR(t7, base, tr[7], 7);
  ADD_ROR(t8, base, tr[8], 8);
  ADD_ROR(t9, base, tr[9], 9);
  ADD_ROR(t10, base, tr[10], 10);
  ADD_ROR(t11, base, tr[11], 11);
  ADD_ROR(t12, base, tr[12], 12);
  ADD_ROR(t13, base, tr[13], 13);
  ADD_ROR(t14, base, tr[14], 14);
  ADD_ROR(t15, base, tr[15], 15);
  // max3-friendly tree: 5 leaf max3 + 2 max3 + 1 max
  float g0 = fmaxf(fmaxf(t0, t1), t2);
  float g1 = fmaxf(fmaxf(t3, t4), t5);
  float g2 = fmaxf(fmaxf(t6, t7), t8);
  float g3 = fmaxf(fmaxf(t9, t10), t11);
  float g4 = fmaxf(fmaxf(t12, t13), t14);
  float h0 = fmaxf(fmaxf(g0, g1), g2);
  float h1 = fmaxf(fmaxf(g3, g4), t15);
  return fmaxf(h0, h1);
}

__device__ __forceinline__ float step_dpp(const float (&trb)[4][16], float d, float f) {
  float a = d, b = d;
  asm("v_permlane32_swap_b32 %0, %1" : "+v"(a), "+v"(b));
  // issue row-swaps early; needed only after the a/b reductions
  int sai = __builtin_amdgcn_ds_swizzle(__float_as_int(a), 0x401F);  // lane^16
  int sbi = __builtin_amdgcn_ds_swizzle(__float_as_int(b), 0x401F);
  float acc0 = reduce16(a, trb[0]);
  float acc1 = reduce16(b, trb[1]);
  float acc2 = reduce16(__int_as_float(sai), trb[2]);
  float acc3 = reduce16(__int_as_float(sbi), trb[3]);
  return fmaxf(fmaxf(fmaxf(acc0, acc1), acc2), acc3) + f;
}

// ---- exact fallback step (R7 structure; used only if probe coverage fails) --
__device__ __forceinline__ float step_lds(const f32x2 (&tr2)[kL / 2], float* dl,
                                          const f32x4* dl4, int i, float d, float f) {
  asm volatile("" ::: "memory");
  dl[i] = d;
  asm volatile("" ::: "memory");
  f32x4 v[16];
#pragma unroll
  for (int q = 0; q < 16; ++q) v[q] = dl4[q];
  __builtin_amdgcn_sched_barrier(0);
  f32x2 mm[16];
#pragma unroll
  for (int q = 0; q < 16; ++q) {
    f32x2 p = tr2[2 * q] + v[q].lo;
    f32x2 r = tr2[2 * q + 1] + v[q].hi;
    mm[q] = __builtin_elementwise_max(p, r);
  }
#pragma unroll
  for (int s = 8; s; s >>= 1)
    for (int q = 0; q < s; ++q) mm[q] = __builtin_elementwise_max(mm[q], mm[q + s]);
  return fmaxf(mm[0].x, mm[0].y) + f;
}

__global__ __launch_bounds__(64, 1) void fwd_delta(const float* __restrict__ feats,
                                                   const float* __restrict__ trans,
                                                   float* __restrict__ delta) {
  const int i = threadIdx.x;
  const int b = blockIdx.x;
  const size_t kBL = (size_t)kB * kL;
  __shared__ float dl[kL];

  // ---- probe the broadcast permutation on lane indices ----
  float lane_f = (float)i;
  float pa = lane_f, pb = lane_f;
  asm("v_permlane32_swap_b32 %0, %1" : "+v"(pa), "+v"(pb));
  int psa = __builtin_amdgcn_ds_swizzle(__float_as_int(pa), 0x401F);
  int psb = __builtin_amdgcn_ds_swizzle(__float_as_int(pb), 0x401F);
  float bases[4];
  bases[0] = pa; bases[1] = pb;
  bases[2] = __int_as_float(psa); bases[3] = __int_as_float(psb);
  float fz = 0.0f;
  asm volatile("" : "+v"(fz));  // keep 0 in a VGPR for DPP adds
  float trb[4][16];
  unsigned covLo = 0, covHi = 0;
#define PROBE_K(c, K)                                                           \
  {                                                                             \
    float t;                                                                    \
    ADD_ROR_FIRST(t, bases[c], fz, K);                                          \
    int s = (int)t;                                                             \
    if (s < 32) covLo |= 1u << s; else covHi |= 1u << (s - 32);                 \
    trb[c][K] = trans[i * kL + s];                                              \
  }
#define PROBE_BASE(c)                                                           \
  {                                                                             \
    int s0 = (int)bases[c];                                                     \
    if (s0 < 32) covLo |= 1u << s0; else covHi |= 1u << (s0 - 32);              \
    trb[c][0] = trans[i * kL + s0];                                             \
    PROBE_K(c, 1) PROBE_K(c, 2) PROBE_K(c, 3) PROBE_K(c, 4) PROBE_K(c, 5)       \
    PROBE_K(c, 6) PROBE_K(c, 7) PROBE_K(c, 8) PROBE_K(c, 9) PROBE_K(c, 10)      \
    PROBE_K(c, 11) PROBE_K(c, 12) PROBE_K(c, 13) PROBE_K(c, 14) PROBE_K(c, 15)  \
  }
  PROBE_BASE(0) PROBE_BASE(1) PROBE_BASE(2) PROBE_BASE(3)
#undef PROBE_BASE
#undef PROBE_K
  const bool ok = __all((covLo == 0xFFFFFFFFu) && (covHi == 0xFFFFFFFFu));

  float d = (i == 62) ? 0.0f : kNeg;
  float* drow = delta + (size_t)b * kL + i;  // layout [T][B][L]
  *drow = d;
  drow += kBL;
  const float* fp = feats + (size_t)b * kT * kL + i;
  float f0 = fp[64 * 1], f1 = fp[64 * 2], f2 = fp[64 * 3], f3 = fp[64 * 4];
  const float* pf = fp + 64 * 5;

  if (ok) {
    for (int it = 0; it < 1022; ++it) {
      d = step_dpp(trb, d, f0);
      *drow = d; drow += kBL; f0 = pf[0];
      d = step_dpp(trb, d, f1);
      *drow = d; drow += kBL; f1 = pf[64];
      d = step_dpp(trb, d, f2);
      *drow = d; drow += kBL; f2 = pf[128];
      d = step_dpp(trb, d, f3);
      *drow = d; drow += kBL; f3 = pf[192];
      pf += 256;
    }
    float g0 = pf[0], g1 = pf[64], g2 = pf[128];
    d = step_dpp(trb, d, f0); *drow = d; drow += kBL;
    d = step_dpp(trb, d, f1); *drow = d; drow += kBL;
    d = step_dpp(trb, d, f2); *drow = d; drow += kBL;
    d = step_dpp(trb, d, f3); *drow = d; drow += kBL;
    d = step_dpp(trb, d, g0); *drow = d; drow += kBL;
    d = step_dpp(trb, d, g1); *drow = d; drow += kBL;
    d = step_dpp(trb, d, g2); *drow = d;
  } else {
    // exact fallback: R7 LDS-broadcast path
    f32x2 tr2[kL / 2];
#pragma unroll
    for (int k = 0; k < kL; k += 4) {
      float4 v = *reinterpret_cast<const float4*>(trans + i * kL + k);
      tr2[k / 2].x = v.x; tr2[k / 2].y = v.y;
      tr2[k / 2 + 1].x = v.z; tr2[k / 2 + 1].y = v.w;
    }
    const f32x4* dl4 = reinterpret_cast<const f32x4*>(dl);
    for (int it = 0; it < 1022; ++it) {
      d = step_lds(tr2, dl, dl4, i, d, f0);
      *drow = d; drow += kBL; f0 = pf[0];
      d = step_lds(tr2, dl, dl4, i, d, f1);
      *drow = d; drow += kBL; f1 = pf[64];
      d = step_lds(tr2, dl, dl4, i, d, f2);
      *drow = d; drow += kBL; f2 = pf[128];
      d = step_lds(tr2, dl, dl4, i, d, f3);
      *drow = d; drow += kBL; f3 = pf[192];
      pf += 256;
    }
    float g0 = pf[0], g1 = pf[64], g2 = pf[128];
    d = step_lds(tr2, dl, dl4, i, d, f0); *drow = d; drow += kBL;
    d = step_lds(tr2, dl, dl4, i, d, f1); *drow = d; drow += kBL;
    d = step_lds(tr2, dl, dl4, i, d, f2); *drow = d; drow += kBL;
    d = step_lds(tr2, dl, dl4, i, d, f3); *drow = d; drow += kBL;
    d = step_lds(tr2, dl, dl4, i, d, g0); *drow = d; drow += kBL;
    d = step_lds(tr2, dl, dl4, i, d, g1); *drow = d; drow += kBL;
    d = step_lds(tr2, dl, dl4, i, d, g2); *drow = d;
  }
}

// ---------------- K1B: forward with argmax (plan B fallback) ----------------
__device__ __forceinline__ void step_b(const float (&tr)[kL], float2* dl2, int i,
                                       float fcur, unsigned char*& prow, float& dcur) {
  asm volatile("s_waitcnt lgkmcnt(0)" ::: "memory");
  float bA = -INFINITY, bBv = -INFINITY;
  int iA = 0, iB = 32;
#pragma unroll
  for (int p = 0; p < 16; ++p) {
    float2 q = dl2[p];
    float c0 = tr[2 * p] + q.x;
    bool g0 = c0 > bA; bA = g0 ? c0 : bA; iA = g0 ? 2 * p : iA;
    float c1 = tr[2 * p + 1] + q.y;
    bool g1 = c1 > bA; bA = g1 ? c1 : bA; iA = g1 ? 2 * p + 1 : iA;
  }
#pragma unroll
  for (int p = 16; p < 32; ++p) {
    float2 q = dl2[p];
    float c0 = tr[2 * p] + q.x;
    bool g0 = c0 > bBv; bBv = g0 ? c0 : bBv; iB = g0 ? 2 * p : iB;
    float c1 = tr[2 * p + 1] + q.y;
    bool g1 = c1 > bBv; bBv = g1 ? c1 : bBv; iB = g1 ? 2 * p + 1 : iB;
  }
  bool gm = bBv > bA;  // strict: tie keeps lower-j half
  float nd = (gm ? bBv : bA) + fcur;
  *prow = (unsigned char)(gm ? iB : iA);
  prow += (size_t)kB * kL;
  asm volatile("s_waitcnt lgkmcnt(0)" ::: "memory");
  reinterpret_cast<float*>(dl2)[i] = nd;
  dcur = nd;
}

__global__ __launch_bounds__(64) void fwd_psi(const float* __restrict__ feats,
                                              const float* __restrict__ trans,
                                              unsigned char* __restrict__ psi,
                                              float* __restrict__ dfin) {
  const int i = threadIdx.x;
  const int b = blockIdx.x;
  float tr[kL];
#pragma unroll
  for (int k = 0; k < kL; k += 4) {
    float4 v = *reinterpret_cast<const float4*>(trans + i * kL + k);
    tr[k] = v.x; tr[k + 1] = v.y; tr[k + 2] = v.z; tr[k + 3] = v.w;
  }
  __shared__ float2 dl2[kL / 2];
  const float d0 = (i == 62) ? 0.0f : kNeg;
  reinterpret_cast<float*>(dl2)[i] = d0;
  unsigned char* prow = psi + (size_t)b * kL + i;
  const float* fb = feats + (size_t)b * kT * kL + i;
  float dcur = d0;
  float f0 = fb[(size_t)kL * 1], f1 = fb[(size_t)kL * 2];
  float f2 = fb[(size_t)kL * 3], f3 = fb[(size_t)kL * 4];
  int t = 1;
  for (int it = 0; it < 1023; ++it, t += 4) {
    step_b(tr, dl2, i, f0, prow, dcur);
    f0 = fb[(size_t)kL * (t + 4 < kT ? t + 4 : kT - 1)];
    step_b(tr, dl2, i, f1, prow, dcur);
    f1 = fb[(size_t)kL * (t + 5 < kT ? t + 5 : kT - 1)];
    step_b(tr, dl2, i, f2, prow, dcur);
    f2 = fb[(size_t)kL * (t + 6 < kT ? t + 6 : kT - 1)];
    step_b(tr, dl2, i, f3, prow, dcur);
    f3 = fb[(size_t)kL * (t + 7 < kT ? t + 7 : kT - 1)];
  }
  step_b(tr, dl2, i, f0, prow, dcur);
  step_b(tr, dl2, i, f1, prow, dcur);
  step_b(tr, dl2, i, f2, prow, dcur);
  dfin[(size_t)b * kL + i] = dcur;
}

// ---------------- K2: recompute backpointers from stored delta (plan A) ------
__global__ __launch_bounds__(256) void psi_from_delta(const float* __restrict__ delta,
                                                      const float* __restrict__ trans,
                                                      unsigned char* __restrict__ psi) {
  const int lane = threadIdx.x & 63;
  const int w = __builtin_amdgcn_readfirstlane(blockIdx.x * 4 + (threadIdx.x >> 6));
  float tr[kL];
#pragma unroll
  for (int k = 0; k < kL; k += 4) {
    float4 v = *reinterpret_cast<const float4*>(trans + lane * kL + k);
    tr[k] = v.x; tr[k + 1] = v.y; tr[k + 2] = v.z; tr[k + 3] = v.w;
  }
  const int r0 = w * 8;  // 8 rows per wave; grid sized exactly
  for (int rr = 0; rr < 8; ++rr) {
    const int r = r0 + rr;
    const float4* row4 = reinterpret_cast<const float4*>(delta + (size_t)r * kL);
    float bA = -INFINITY, bBv = -INFINITY;
    int iA = 0, iB = 32;
#pragma unroll
    for (int q = 0; q < 8; ++q) {
      float4 dv = row4[q];
      float c; bool g;
      c = tr[4 * q + 0] + dv.x; g = c > bA; bA = g ? c : bA; iA = g ? 4 * q + 0 : iA;
      c = tr[4 * q + 1] + dv.y; g = c > bA; bA = g ? c : bA; iA = g ? 4 * q + 1 : iA;
      c = tr[4 * q + 2] + dv.z; g = c > bA; bA = g ? c : bA; iA = g ? 4 * q + 2 : iA;
      c = tr[4 * q + 3] + dv.w; g = c > bA; bA = g ? c : bA; iA = g ? 4 * q + 3 : iA;
    }
#pragma unroll
    for (int q = 8; q < 16; ++q) {
      float4 dv = row4[q];
      float c; bool g;
      c = tr[4 * q + 0] + dv.x; g = c > bBv; bBv = g ? c : bBv; iB = g ? 4 * q + 0 : iB;
      c = tr[4 * q + 1] + dv.y; g = c > bBv; bBv = g ? c : bBv; iB = g ? 4 * q + 1 : iB;
      c = tr[4 * q + 2] + dv.z; g = c > bBv; bBv = g ? c : bBv; iB = g ? 4 * q + 2 : iB;
      c = tr[4 * q + 3] + dv.w; g = c > bBv; bBv = g ? c : bBv; iB = g ? 4 * q + 3 : iB;
    }
    bool gm = bBv > bA;  // tie -> lower half (first occurrence)
    psi[(size_t)r * kL + lane] = (unsigned char)(gm ? iB : iA);
  }
}

// ---------------- K3: segment composition (in-place psi -> M) ----------------
__global__ __launch_bounds__(256) void seg_compose(unsigned char* psiM,
                                                   unsigned char* __restrict__ C) {
  const int lane = threadIdx.x & 63;
  const int w = blockIdx.x * 4 + (threadIdx.x >> 6);
  const int s = w >> 7;
  const int b = w & 127;
  const int tstart = s * kSegLen;
  const int tend = (tstart + kSegLen < kT) ? tstart + kSegLen : kT - 1;  // last seg: 4095
  const size_t stride = (size_t)kB * kL;
  size_t off = ((size_t)(tend - 1) * kB + b) * kL + lane;
  int m = lane;
  int v = psiM[off];
  for (int t = tend - 1; t > tstart; --t) {
    int vn = psiM[off - stride];          // prefetch next row
    m = __shfl(v, m, 64);                 // m = psi_row[m]
    psiM[off] = (unsigned char)m;         // M[t][b][e] = path[t] | hyp e
    v = vn;
    off -= stride;
  }
  m = __shfl(v, m, 64);
  psiM[off] = (unsigned char)m;
  C[((size_t)s * kB + b) * kL + lane] = (unsigned char)m;  // composed map
}

// ---------------- K4: score, last label, boundary-label scan ----------------
__global__ __launch_bounds__(64) void score_scan(const float* __restrict__ dfin,
                                                 const unsigned char* __restrict__ C,
                                                 int* __restrict__ E,
                                                 float* __restrict__ out) {
  const int b = blockIdx.x;
  const int i = threadIdx.x;
  float d = dfin[(size_t)b * kL + i];
  float m = d;
#pragma unroll
  for (int off = 32; off; off >>= 1) m = fmaxf(m, __shfl_xor(m, off, 64));
  unsigned long long msk = __ballot(d == m);
  int ll = __ffsll(msk) - 1;  // first (lowest) argmax lane
  if (i == 0) {
    out[b] = m;
    out[kB + (size_t)b * kT + (kT - 1)] = (float)ll;
    int lbl = ll;
    for (int s = kSeg - 1; s >= 0; --s) {
      E[s * kB + b] = lbl;                              // label at t_end(s)
      lbl = C[((size_t)s * kB + b) * kL + lbl];         // -> label at t_start(s)
    }
  }
}

// ---------------- K5: parallel path gather ----------------
__global__ __launch_bounds__(256) void path_fill(const unsigned char* __restrict__ M,
                                                 const int* __restrict__ E,
                                                 float* __restrict__ out) {
  const int n = blockIdx.x * 256 + threadIdx.x;  // n = b*4096 + t
  const int b = n >> 12;
  const int t = n & (kT - 1);
  if (t == kT - 1) return;  // written by score_scan
  const int e = E[(t >> 6) * kB + b];
  const unsigned char lab = M[((size_t)t * kB + b) * kL + e];
  out[kB + (size_t)b * kT + t] = (float)lab;
}

extern "C" void kernel_launch(void* const* d_in, const int* in_sizes, int n_in,
                              void* d_out, int out_size, void* d_ws, size_t ws_size,
                              hipStream_t stream) {
  const float* feats = (const float*)d_in[0];
  const float* trans = (const float*)d_in[1];
  float* out = (float*)d_out;
  char* ws = (char*)d_ws;

  const size_t deltaB = (size_t)kT * kB * kL * 4;   // 134,217,728
  const size_t psiB   = (size_t)kT * kB * kL;       //  33,554,432
  const size_t CBy    = (size_t)kSeg * kB * kL;     //     524,288
  const size_t EBy    = (size_t)kSeg * kB * 4;      //      32,768

  if (ws_size >= deltaB + psiB + CBy + EBy) {
    // Plan A: value-only forward + fully-parallel backpointer recompute.
    float* delta = (float*)ws;
    unsigned char* psi = (unsigned char*)(ws + deltaB);
    unsigned char* C = (unsigned char*)(ws + deltaB + psiB);
    int* E = (int*)(ws + deltaB + psiB + CBy);
    hipLaunchKernelGGL(fwd_delta, dim3(kB), dim3(64), 0, stream, feats, trans, delta);
    hipLaunchKernelGGL(psi_from_delta, dim3(16380), dim3(256), 0, stream, delta, trans, psi);
    hipLaunchKernelGGL(seg_compose, dim3(2048), dim3(256), 0, stream, psi, C);
    hipLaunchKernelGGL(score_scan, dim3(kB), dim3(64), 0, stream,
                       delta + (size_t)(kT - 1) * kB * kL, C, E, out);
    hipLaunchKernelGGL(path_fill, dim3(2048), dim3(256), 0, stream, psi, E, out);
  } else {
    // Plan B: argmax in forward (psi only, ~34 MB workspace).
    unsigned char* psi = (unsigned char*)ws;
    unsigned char* C = (unsigned char*)(ws + psiB);
    int* E = (int*)(ws + psiB + CBy);
    float* dfin = (float*)(ws + psiB + CBy + EBy);
    hipLaunchKernelGGL(fwd_psi, dim3(kB), dim3(64), 0, stream, feats, trans, psi, dfin);
    hipLaunchKernelGGL(seg_compose, dim3(2048), dim3(256), 0, stream, psi, C);
    hipLaunchKernelGGL(score_scan, dim3(kB), dim3(64), 0, stream, dfin, C, E, out);
    hipLaunchKernelGGL(path_fill, dim3(2048), dim3(256), 0, stream, psi, E, out);
  }
}

// Round 9
// 1266.211 us; speedup vs baseline: 1.1024x; 1.1024x over previous
//
#include <hip/hip_runtime.h>

// Viterbi decode (CRF): B=128, T=4096, L=64.
// Outputs: score[B] (f32), path[B][T] (written as float labels).
constexpr int kB = 128;
constexpr int kT = 4096;
constexpr int kL = 64;
constexpr int kSeg = 64;     // number of backtrace segments
constexpr int kSegLen = 64;  // rows per segment (last segment has 63)
constexpr float kNeg = -10000.0f;

typedef float f32x2 __attribute__((ext_vector_type(2)));
typedef float f32x4 __attribute__((ext_vector_type(4)));

// ---------------- K1A forward: all-VALU broadcast (builtin DPP) -------------
// Lane i owns label i; delta in ONE register. Broadcast:
//   (a,b) = permlane32_swap(d,d)  [builtin, VALU]
//   sa,sb = ds_swizzle xor-16 of a,b  [2 DS ops; latency hidden under a/b work]
// Per 16-lane row the 4 bases hold 4 distinct 16-label chunks; 15 update_dpp
// row_ror + add (backend fuses to v_add_f32_dpp, with hazard wait-states
// inserted by the compiler — R8's raw-asm s_nop placement was reorderable and
// corrupted results). trb gathered at init in PROBED order; step t=1 is
// bitwise-verified against the exact LDS path, else full fallback.

template <int K>
__device__ __forceinline__ int rotidx(int v) {
  // row_ror:K  (DPP ctrl 0x120|K), all rows/banks, bound_ctrl on (no OOB lanes)
  return __builtin_amdgcn_update_dpp(0, v, 0x120 | K, 0xF, 0xF, true);
}
template <int K>
__device__ __forceinline__ float rotadd(float base, float tr) {
  return __int_as_float(rotidx<K>(__float_as_int(base))) + tr;
}

__device__ __forceinline__ float reduce16b(float base, const float (&tr)[16]) {
  float t0 = base + tr[0];
  float t1 = rotadd<1>(base, tr[1]);
  float t2 = rotadd<2>(base, tr[2]);
  float t3 = rotadd<3>(base, tr[3]);
  float t4 = rotadd<4>(base, tr[4]);
  float t5 = rotadd<5>(base, tr[5]);
  float t6 = rotadd<6>(base, tr[6]);
  float t7 = rotadd<7>(base, tr[7]);
  float t8 = rotadd<8>(base, tr[8]);
  float t9 = rotadd<9>(base, tr[9]);
  float t10 = rotadd<10>(base, tr[10]);
  float t11 = rotadd<11>(base, tr[11]);
  float t12 = rotadd<12>(base, tr[12]);
  float t13 = rotadd<13>(base, tr[13]);
  float t14 = rotadd<14>(base, tr[14]);
  float t15 = rotadd<15>(base, tr[15]);
  float g0 = fmaxf(fmaxf(t0, t1), t2);     // v_max3_f32
  float g1 = fmaxf(fmaxf(t3, t4), t5);
  float g2 = fmaxf(fmaxf(t6, t7), t8);
  float g3 = fmaxf(fmaxf(t9, t10), t11);
  float g4 = fmaxf(fmaxf(t12, t13), t14);
  float h0 = fmaxf(fmaxf(g0, g1), g2);
  float h1 = fmaxf(fmaxf(g3, g4), t15);
  return fmaxf(h0, h1);
}

__device__ __forceinline__ float step_plane(const float (&trb)[4][16], float d, float f) {
  auto w32 = __builtin_amdgcn_permlane32_swap(__float_as_uint(d), __float_as_uint(d),
                                              false, false);
  int a = (int)w32[0], bb = (int)w32[1];
  int sa = __builtin_amdgcn_ds_swizzle(a, 0x401F);   // lane^16 (issued early)
  int sb = __builtin_amdgcn_ds_swizzle(bb, 0x401F);
  float acc0 = reduce16b(__int_as_float(a), trb[0]);
  float acc1 = reduce16b(__int_as_float(bb), trb[1]);
  float acc2 = reduce16b(__int_as_float(sa), trb[2]);
  float acc3 = reduce16b(__int_as_float(sb), trb[3]);
  return fmaxf(fmaxf(acc0, acc1), fmaxf(acc2, acc3)) + f;
}

// ---- exact step (R7 structure; verify reference + full fallback) -----------
__device__ __forceinline__ float step_lds(const f32x2 (&tr2)[kL / 2], float* dl,
                                          const f32x4* dl4, int i, float d, float f) {
  asm volatile("" ::: "memory");
  dl[i] = d;
  asm volatile("" ::: "memory");
  f32x4 v[16];
#pragma unroll
  for (int q = 0; q < 16; ++q) v[q] = dl4[q];
  __builtin_amdgcn_sched_barrier(0);
  f32x2 mm[16];
#pragma unroll
  for (int q = 0; q < 16; ++q) {
    f32x2 p = tr2[2 * q] + v[q].lo;
    f32x2 r = tr2[2 * q + 1] + v[q].hi;
    mm[q] = __builtin_elementwise_max(p, r);
  }
#pragma unroll
  for (int s = 8; s; s >>= 1)
    for (int q = 0; q < s; ++q) mm[q] = __builtin_elementwise_max(mm[q], mm[q + s]);
  return fmaxf(mm[0].x, mm[0].y) + f;
}

__global__ __launch_bounds__(64, 1) void fwd_delta(const float* __restrict__ feats,
                                                   const float* __restrict__ trans,
                                                   float* __restrict__ delta) {
  const int i = threadIdx.x;
  const int b = blockIdx.x;
  const size_t kBL = (size_t)kB * kL;
  __shared__ float dl[kL];
  const f32x4* dl4 = reinterpret_cast<const f32x4*>(dl);

  // ---- probe the broadcast on lane indices (same builtins as the step) ----
  auto w32p = __builtin_amdgcn_permlane32_swap((unsigned)i, (unsigned)i, false, false);
  const int pa = (int)w32p[0], pbv = (int)w32p[1];
  const int psa = __builtin_amdgcn_ds_swizzle(pa, 0x401F);
  const int psb = __builtin_amdgcn_ds_swizzle(pbv, 0x401F);
  float trb[4][16];
  unsigned long long cov = 0;
#define PK1(c, baseint, K)                                                      \
  { int s = rotidx<K>(baseint) & 63; cov |= 1ull << s;                          \
    trb[c][K] = trans[i * kL + s]; }
#define PCHUNK(c, baseint)                                                      \
  { int s0 = (baseint) & 63; cov |= 1ull << s0; trb[c][0] = trans[i * kL + s0]; \
    PK1(c, baseint, 1) PK1(c, baseint, 2) PK1(c, baseint, 3)                    \
    PK1(c, baseint, 4) PK1(c, baseint, 5) PK1(c, baseint, 6)                    \
    PK1(c, baseint, 7) PK1(c, baseint, 8) PK1(c, baseint, 9)                    \
    PK1(c, baseint, 10) PK1(c, baseint, 11) PK1(c, baseint, 12)                 \
    PK1(c, baseint, 13) PK1(c, baseint, 14) PK1(c, baseint, 15) }
  PCHUNK(0, pa) PCHUNK(1, pbv) PCHUNK(2, psa) PCHUNK(3, psb)
#undef PCHUNK
#undef PK1
  bool ok = __all(cov == 0xFFFFFFFFFFFFFFFFull) != 0;

  // transitions row for verify + fallback (dead in the ok-loop)
  f32x2 tr2[kL / 2];
#pragma unroll
  for (int k = 0; k < kL; k += 4) {
    float4 v = *reinterpret_cast<const float4*>(trans + i * kL + k);
    tr2[k / 2].x = v.x; tr2[k / 2].y = v.y;
    tr2[k / 2 + 1].x = v.z; tr2[k / 2 + 1].y = v.w;
  }

  float d = (i == 62) ? 0.0f : kNeg;
  float* drow = delta + (size_t)b * kL + i;  // layout [T][B][L]
  *drow = d;
  drow += kBL;
  const float* fp = feats + (size_t)b * kT * kL + i;
  float fA = fp[64 * 1], fB = fp[64 * 2], fC = fp[64 * 3], fD = fp[64 * 4];

  // ---- verify step t=1: DPP path vs exact LDS path, bitwise ----
  float dA = step_plane(trb, d, fA);
  float dB = step_lds(tr2, dl, dl4, i, d, fA);
  ok = ok && (__all(__float_as_int(dA) == __float_as_int(dB)) != 0);
  d = dB;
  *drow = d;
  drow += kBL;
  fA = fp[64 * 5];
  const float* pf = fp + 64 * 6;

  if (ok) {
    for (int it = 0; it < 1022; ++it) {  // steps t=2..4089
      d = step_plane(trb, d, fB); *drow = d; drow += kBL; fB = pf[0];
      d = step_plane(trb, d, fC); *drow = d; drow += kBL; fC = pf[64];
      d = step_plane(trb, d, fD); *drow = d; drow += kBL; fD = pf[128];
      d = step_plane(trb, d, fA); *drow = d; drow += kBL; fA = pf[192];
      pf += 256;
    }
    float g0 = pf[0], g1 = pf[64];  // t=4094, 4095
    d = step_plane(trb, d, fB); *drow = d; drow += kBL;
    d = step_plane(trb, d, fC); *drow = d; drow += kBL;
    d = step_plane(trb, d, fD); *drow = d; drow += kBL;
    d = step_plane(trb, d, fA); *drow = d; drow += kBL;
    d = step_plane(trb, d, g0); *drow = d; drow += kBL;
    d = step_plane(trb, d, g1); *drow = d;
  } else {
    for (int it = 0; it < 1022; ++it) {
      d = step_lds(tr2, dl, dl4, i, d, fB); *drow = d; drow += kBL; fB = pf[0];
      d = step_lds(tr2, dl, dl4, i, d, fC); *drow = d; drow += kBL; fC = pf[64];
      d = step_lds(tr2, dl, dl4, i, d, fD); *drow = d; drow += kBL; fD = pf[128];
      d = step_lds(tr2, dl, dl4, i, d, fA); *drow = d; drow += kBL; fA = pf[192];
      pf += 256;
    }
    float g0 = pf[0], g1 = pf[64];
    d = step_lds(tr2, dl, dl4, i, d, fB); *drow = d; drow += kBL;
    d = step_lds(tr2, dl, dl4, i, d, fC); *drow = d; drow += kBL;
    d = step_lds(tr2, dl, dl4, i, d, fD); *drow = d; drow += kBL;
    d = step_lds(tr2, dl, dl4, i, d, fA); *drow = d; drow += kBL;
    d = step_lds(tr2, dl, dl4, i, d, g0); *drow = d; drow += kBL;
    d = step_lds(tr2, dl, dl4, i, d, g1); *drow = d;
  }
}

// ---------------- K2: recompute backpointers from stored delta --------------
// row r = t*128 + b; delta layout [T][B][L] makes row base = delta + r*64.
__global__ __launch_bounds__(256) void psi_from_delta(const float* __restrict__ delta,
                                                      const float* __restrict__ trans,
                                                      unsigned char* __restrict__ psi) {
  const int lane = threadIdx.x & 63;
  const int w = __builtin_amdgcn_readfirstlane(blockIdx.x * 4 + (threadIdx.x >> 6));
  float tr[kL];
#pragma unroll
  for (int k = 0; k < kL; k += 4) {
    float4 v = *reinterpret_cast<const float4*>(trans + lane * kL + k);
    tr[k] = v.x; tr[k + 1] = v.y; tr[k + 2] = v.z; tr[k + 3] = v.w;
  }
  const int r0 = w * 8;  // 8 rows per wave; grid sized exactly
  for (int rr = 0; rr < 8; ++rr) {
    const int r = r0 + rr;
    const float4* row4 = reinterpret_cast<const float4*>(delta + (size_t)r * kL);
    float bA = -INFINITY, bBv = -INFINITY;
    int iA = 0, iB = 32;
#pragma unroll
    for (int q = 0; q < 8; ++q) {
      float4 dv = row4[q];
      float c; bool g;
      c = tr[4 * q + 0] + dv.x; g = c > bA; bA = g ? c : bA; iA = g ? 4 * q + 0 : iA;
      c = tr[4 * q + 1] + dv.y; g = c > bA; bA = g ? c : bA; iA = g ? 4 * q + 1 : iA;
      c = tr[4 * q + 2] + dv.z; g = c > bA; bA = g ? c : bA; iA = g ? 4 * q + 2 : iA;
      c = tr[4 * q + 3] + dv.w; g = c > bA; bA = g ? c : bA; iA = g ? 4 * q + 3 : iA;
    }
#pragma unroll
    for (int q = 8; q < 16; ++q) {
      float4 dv = row4[q];
      float c; bool g;
      c = tr[4 * q + 0] + dv.x; g = c > bBv; bBv = g ? c : bBv; iB = g ? 4 * q + 0 : iB;
      c = tr[4 * q + 1] + dv.y; g = c > bBv; bBv = g ? c : bBv; iB = g ? 4 * q + 1 : iB;
      c = tr[4 * q + 2] + dv.z; g = c > bBv; bBv = g ? c : bBv; iB = g ? 4 * q + 2 : iB;
      c = tr[4 * q + 3] + dv.w; g = c > bBv; bBv = g ? c : bBv; iB = g ? 4 * q + 3 : iB;
    }
    bool gm = bBv > bA;  // tie -> lower half (first occurrence)
    psi[(size_t)r * kL + lane] = (unsigned char)(gm ? iB : iA);
  }
}

// ---------------- K3: segment composition (in-place psi -> M) ----------------
__global__ __launch_bounds__(256) void seg_compose(unsigned char* psiM,
                                                   unsigned char* __restrict__ C) {
  const int lane = threadIdx.x & 63;
  const int w = blockIdx.x * 4 + (threadIdx.x >> 6);
  const int s = w >> 7;
  const int b = w & 127;
  const int tstart = s * kSegLen;
  const int tend = (tstart + kSegLen < kT) ? tstart + kSegLen : kT - 1;  // last seg: 4095
  const size_t stride = (size_t)kB * kL;
  size_t off = ((size_t)(tend - 1) * kB + b) * kL + lane;
  int m = lane;
  int v = psiM[off];
  for (int t = tend - 1; t > tstart; --t) {
    int vn = psiM[off - stride];          // prefetch next row
    m = __shfl(v, m, 64);                 // m = psi_row[m]
    psiM[off] = (unsigned char)m;         // M[t][b][e] = path[t] | hyp e
    v = vn;
    off -= stride;
  }
  m = __shfl(v, m, 64);
  psiM[off] = (unsigned char)m;
  C[((size_t)s * kB + b) * kL + lane] = (unsigned char)m;  // composed map
}

// ---------------- K4: score, last label, boundary-label scan ----------------
__global__ __launch_bounds__(64) void score_scan(const float* __restrict__ dfin,
                                                 const unsigned char* __restrict__ C,
                                                 int* __restrict__ E,
                                                 float* __restrict__ out) {
  const int b = blockIdx.x;
  const int i = threadIdx.x;
  float d = dfin[(size_t)b * kL + i];
  float m = d;
#pragma unroll
  for (int off = 32; off; off >>= 1) m = fmaxf(m, __shfl_xor(m, off, 64));
  unsigned long long msk = __ballot(d == m);
  int ll = __ffsll(msk) - 1;  // first (lowest) argmax lane
  if (i == 0) {
    out[b] = m;
    out[kB + (size_t)b * kT + (kT - 1)] = (float)ll;
    int lbl = ll;
    for (int s = kSeg - 1; s >= 0; --s) {
      E[s * kB + b] = lbl;                              // label at t_end(s)
      lbl = C[((size_t)s * kB + b) * kL + lbl];         // -> label at t_start(s)
    }
  }
}

// ---------------- K5: parallel path gather ----------------
__global__ __launch_bounds__(256) void path_fill(const unsigned char* __restrict__ M,
                                                 const int* __restrict__ E,
                                                 float* __restrict__ out) {
  const int n = blockIdx.x * 256 + threadIdx.x;  // n = b*4096 + t
  const int b = n >> 12;
  const int t = n & (kT - 1);
  if (t == kT - 1) return;  // written by score_scan
  const int e = E[(t >> 6) * kB + b];
  const unsigned char lab = M[((size_t)t * kB + b) * kL + e];
  out[kB + (size_t)b * kT + t] = (float)lab;
}

extern "C" void kernel_launch(void* const* d_in, const int* in_sizes, int n_in,
                              void* d_out, int out_size, void* d_ws, size_t ws_size,
                              hipStream_t stream) {
  const float* feats = (const float*)d_in[0];
  const float* trans = (const float*)d_in[1];
  float* out = (float*)d_out;
  char* ws = (char*)d_ws;

  const size_t deltaB = (size_t)kT * kB * kL * 4;   // 134,217,728
  const size_t psiB   = (size_t)kT * kB * kL;       //  33,554,432
  const size_t CBy    = (size_t)kSeg * kB * kL;     //     524,288
  const size_t EBy    = (size_t)kSeg * kB * 4;      //      32,768

  // Plan A: value-only forward + fully-parallel backpointer recompute.
  float* delta = (float*)ws;
  unsigned char* psi = (unsigned char*)(ws + deltaB);
  unsigned char* C = (unsigned char*)(ws + deltaB + psiB);
  int* E = (int*)(ws + deltaB + psiB + CBy);
  (void)psiB; (void)CBy; (void)EBy;
  hipLaunchKernelGGL(fwd_delta, dim3(kB), dim3(64), 0, stream, feats, trans, delta);
  hipLaunchKernelGGL(psi_from_delta, dim3(16380), dim3(256), 0, stream, delta, trans, psi);
  hipLaunchKernelGGL(seg_compose, dim3(2048), dim3(256), 0, stream, psi, C);
  hipLaunchKernelGGL(score_scan, dim3(kB), dim3(64), 0, stream,
                     delta + (size_t)(kT - 1) * kB * kL, C, E, out);
  hipLaunchKernelGGL(path_fill, dim3(2048), dim3(256), 0, stream, psi, E, out);
}

// Round 10
// 1258.473 us; speedup vs baseline: 1.1092x; 1.0061x over previous
//
#include <hip/hip_runtime.h>

// Viterbi decode (CRF): B=128, T=4096, L=64.
// Outputs: score[B] (f32), path[B][T] (written as float labels).
constexpr int kB = 128;
constexpr int kT = 4096;
constexpr int kL = 64;
constexpr int kSeg = 64;     // number of backtrace segments
constexpr int kSegLen = 64;  // rows per segment (last segment has 63)
constexpr float kNeg = -10000.0f;

typedef float f32x2 __attribute__((ext_vector_type(2)));
typedef float f32x4 __attribute__((ext_vector_type(4)));

#if __has_builtin(__builtin_amdgcn_permlane16_swap)
#define HAS_PL16 1
#else
#define HAS_PL16 0
#endif

// ---------------- K1A forward: all-VALU broadcast (builtin DPP) -------------
// Lane i owns label i; delta in ONE register. Bases (4 regs, per 16-lane row
// holding 4 distinct 16-label chunks) built by:
//   tier A: permlane32_swap + 2x permlane16_swap   (3 VALU ops, zero DS)
//   tier B: permlane32_swap + 2x ds_swizzle xor-16 (R9 path, DS on chain)
//   tier C: exact LDS-broadcast loop (R7)
// trb is gathered at init in PROBED order (probe runs the same builtins on
// lane indices; 64-bit coverage check), then step t=1 is bitwise-verified
// against the exact LDS step. Whole-wave uniform mode select.

template <int K>
__device__ __forceinline__ int rotidx(int v) {
  // row_ror:K  (DPP ctrl 0x120|K), all rows/banks, bound_ctrl on
  return __builtin_amdgcn_update_dpp(0, v, 0x120 | K, 0xF, 0xF, true);
}
template <int K>
__device__ __forceinline__ float rotadd(float base, float tr) {
  return __int_as_float(rotidx<K>(__float_as_int(base))) + tr;
}

__device__ __forceinline__ float reduce16b(float base, const float (&tr)[16]) {
  float t0 = base + tr[0];
  float t1 = rotadd<1>(base, tr[1]);
  float t2 = rotadd<2>(base, tr[2]);
  float t3 = rotadd<3>(base, tr[3]);
  float t4 = rotadd<4>(base, tr[4]);
  float t5 = rotadd<5>(base, tr[5]);
  float t6 = rotadd<6>(base, tr[6]);
  float t7 = rotadd<7>(base, tr[7]);
  float t8 = rotadd<8>(base, tr[8]);
  float t9 = rotadd<9>(base, tr[9]);
  float t10 = rotadd<10>(base, tr[10]);
  float t11 = rotadd<11>(base, tr[11]);
  float t12 = rotadd<12>(base, tr[12]);
  float t13 = rotadd<13>(base, tr[13]);
  float t14 = rotadd<14>(base, tr[14]);
  float t15 = rotadd<15>(base, tr[15]);
  float g0 = fmaxf(fmaxf(t0, t1), t2);     // v_max3_f32
  float g1 = fmaxf(fmaxf(t3, t4), t5);
  float g2 = fmaxf(fmaxf(t6, t7), t8);
  float g3 = fmaxf(fmaxf(t9, t10), t11);
  float g4 = fmaxf(fmaxf(t12, t13), t14);
  float h0 = fmaxf(fmaxf(g0, g1), g2);
  float h1 = fmaxf(fmaxf(g3, g4), t15);
  return fmaxf(h0, h1);
}

#if HAS_PL16
__device__ __forceinline__ float step_planeA(const float (&trb)[4][16], float d, float f) {
  auto w = __builtin_amdgcn_permlane32_swap(__float_as_uint(d), __float_as_uint(d),
                                            false, false);
  auto wa = __builtin_amdgcn_permlane16_swap((unsigned)w[0], (unsigned)w[0], false, false);
  auto wb = __builtin_amdgcn_permlane16_swap((unsigned)w[1], (unsigned)w[1], false, false);
  float acc0 = reduce16b(__uint_as_float(wa[0]), trb[0]);
  float acc1 = reduce16b(__uint_as_float(wa[1]), trb[1]);
  float acc2 = reduce16b(__uint_as_float(wb[0]), trb[2]);
  float acc3 = reduce16b(__uint_as_float(wb[1]), trb[3]);
  return fmaxf(fmaxf(fmaxf(acc0, acc1), acc2), acc3) + f;
}
#endif

__device__ __forceinline__ float step_planeB(const float (&trb)[4][16], float d, float f) {
  auto w32 = __builtin_amdgcn_permlane32_swap(__float_as_uint(d), __float_as_uint(d),
                                              false, false);
  int a = (int)w32[0], bb = (int)w32[1];
  int sa = __builtin_amdgcn_ds_swizzle(a, 0x401F);   // lane^16 (issued early)
  int sb = __builtin_amdgcn_ds_swizzle(bb, 0x401F);
  float acc0 = reduce16b(__int_as_float(a), trb[0]);
  float acc1 = reduce16b(__int_as_float(bb), trb[1]);
  float acc2 = reduce16b(__int_as_float(sa), trb[2]);
  float acc3 = reduce16b(__int_as_float(sb), trb[3]);
  return fmaxf(fmaxf(fmaxf(acc0, acc1), acc2), acc3) + f;
}

// ---- exact step (R7 structure; verify reference + tier-C fallback) ---------
__device__ __forceinline__ float step_lds(const f32x2 (&tr2)[kL / 2], float* dl,
                                          const f32x4* dl4, int i, float d, float f) {
  asm volatile("" ::: "memory");
  dl[i] = d;
  asm volatile("" ::: "memory");
  f32x4 v[16];
#pragma unroll
  for (int q = 0; q < 16; ++q) v[q] = dl4[q];
  __builtin_amdgcn_sched_barrier(0);
  f32x2 mm[16];
#pragma unroll
  for (int q = 0; q < 16; ++q) {
    f32x2 p = tr2[2 * q] + v[q].lo;
    f32x2 r = tr2[2 * q + 1] + v[q].hi;
    mm[q] = __builtin_elementwise_max(p, r);
  }
#pragma unroll
  for (int s = 8; s; s >>= 1)
    for (int q = 0; q < s; ++q) mm[q] = __builtin_elementwise_max(mm[q], mm[q + s]);
  return fmaxf(mm[0].x, mm[0].y) + f;
}

__global__ __launch_bounds__(64, 1) void fwd_delta(const float* __restrict__ feats,
                                                   const float* __restrict__ trans,
                                                   float* __restrict__ delta) {
  const int i = threadIdx.x;
  const int b = blockIdx.x;
  const size_t kBL = (size_t)kB * kL;
  __shared__ float dl[kL];
  const f32x4* dl4 = reinterpret_cast<const f32x4*>(dl);

  float trb[4][16];
  int mode = 0;  // 0=LDS, 1=planeA, 2=planeB

  // helper to test coverage + gather trb for a candidate base-index quad
#define TRY_ARRANGEMENT(b0, b1, b2, b3, MODE)                                   \
  if (mode == 0) {                                                              \
    int baseq[4] = {b0, b1, b2, b3};                                            \
    unsigned long long cov = 0;                                                 \
    _Pragma("unroll") for (int c = 0; c < 4; ++c) {                             \
      int s0 = baseq[c] & 63;                                                   \
      cov |= 1ull << s0;                                                        \
      trb[c][0] = trans[i * kL + s0];                                           \
      int s;                                                                    \
      s = rotidx<1>(baseq[c]) & 63;  cov |= 1ull << s; trb[c][1]  = trans[i * kL + s]; \
      s = rotidx<2>(baseq[c]) & 63;  cov |= 1ull << s; trb[c][2]  = trans[i * kL + s]; \
      s = rotidx<3>(baseq[c]) & 63;  cov |= 1ull << s; trb[c][3]  = trans[i * kL + s]; \
      s = rotidx<4>(baseq[c]) & 63;  cov |= 1ull << s; trb[c][4]  = trans[i * kL + s]; \
      s = rotidx<5>(baseq[c]) & 63;  cov |= 1ull << s; trb[c][5]  = trans[i * kL + s]; \
      s = rotidx<6>(baseq[c]) & 63;  cov |= 1ull << s; trb[c][6]  = trans[i * kL + s]; \
      s = rotidx<7>(baseq[c]) & 63;  cov |= 1ull << s; trb[c][7]  = trans[i * kL + s]; \
      s = rotidx<8>(baseq[c]) & 63;  cov |= 1ull << s; trb[c][8]  = trans[i * kL + s]; \
      s = rotidx<9>(baseq[c]) & 63;  cov |= 1ull << s; trb[c][9]  = trans[i * kL + s]; \
      s = rotidx<10>(baseq[c]) & 63; cov |= 1ull << s; trb[c][10] = trans[i * kL + s]; \
      s = rotidx<11>(baseq[c]) & 63; cov |= 1ull << s; trb[c][11] = trans[i * kL + s]; \
      s = rotidx<12>(baseq[c]) & 63; cov |= 1ull << s; trb[c][12] = trans[i * kL + s]; \
      s = rotidx<13>(baseq[c]) & 63; cov |= 1ull << s; trb[c][13] = trans[i * kL + s]; \
      s = rotidx<14>(baseq[c]) & 63; cov |= 1ull << s; trb[c][14] = trans[i * kL + s]; \
      s = rotidx<15>(baseq[c]) & 63; cov |= 1ull << s; trb[c][15] = trans[i * kL + s]; \
    }                                                                           \
    if (__all(cov == 0xFFFFFFFFFFFFFFFFull)) mode = MODE;                       \
  }

  // probe with lane indices, same builtins as the step functions
  auto wp = __builtin_amdgcn_permlane32_swap((unsigned)i, (unsigned)i, false, false);
#if HAS_PL16
  {
    auto wpa = __builtin_amdgcn_permlane16_swap((unsigned)wp[0], (unsigned)wp[0],
                                                false, false);
    auto wpb = __builtin_amdgcn_permlane16_swap((unsigned)wp[1], (unsigned)wp[1],
                                                false, false);
    TRY_ARRANGEMENT((int)wpa[0], (int)wpa[1], (int)wpb[0], (int)wpb[1], 1)
  }
#endif
  {
    int sa = __builtin_amdgcn_ds_swizzle((int)wp[0], 0x401F);
    int sb = __builtin_amdgcn_ds_swizzle((int)wp[1], 0x401F);
    TRY_ARRANGEMENT((int)wp[0], (int)wp[1], sa, sb, 2)
  }
#undef TRY_ARRANGEMENT

  // transitions row for verify + tier-C (dead in plane loops)
  f32x2 tr2[kL / 2];
#pragma unroll
  for (int k = 0; k < kL; k += 4) {
    float4 v = *reinterpret_cast<const float4*>(trans + i * kL + k);
    tr2[k / 2].x = v.x; tr2[k / 2].y = v.y;
    tr2[k / 2 + 1].x = v.z; tr2[k / 2 + 1].y = v.w;
  }

  float d = (i == 62) ? 0.0f : kNeg;
  float* drow = delta + (size_t)b * kL + i;  // layout [T][B][L]
  *drow = d;
  drow += kBL;
  const float* fp = feats + (size_t)b * kT * kL + i;
  float fA = fp[64 * 1], fB = fp[64 * 2], fC = fp[64 * 3], fD = fp[64 * 4];

  // ---- verify step t=1 bitwise against the exact LDS step ----
  float dP;
#if HAS_PL16
  if (mode == 1) dP = step_planeA(trb, d, fA); else
#endif
  if (mode == 2) dP = step_planeB(trb, d, fA);
  else dP = 0.0f;
  float dE = step_lds(tr2, dl, dl4, i, d, fA);
  if (mode != 0 && !__all(__float_as_int(dP) == __float_as_int(dE))) mode = 0;
  d = dE;
  *drow = d;
  drow += kBL;
  fA = fp[64 * 5];
  const float* pf = fp + 64 * 6;

#define RUN_LOOP(STEP)                                                          \
  {                                                                             \
    for (int it = 0; it < 1022; ++it) { /* steps t=2..4089 */                   \
      d = STEP; *drow = d; drow += kBL; fB = pf[0];                             \
      { float& fX = fC; d = STEP##_2; *drow = d; drow += kBL; fX = pf[64]; }    \
    }                                                                           \
  }
  // (macro gymnastics avoided: write the three loops explicitly)

#if HAS_PL16
  if (mode == 1) {
    for (int it = 0; it < 1022; ++it) {
      d = step_planeA(trb, d, fB); *drow = d; drow += kBL; fB = pf[0];
      d = step_planeA(trb, d, fC); *drow = d; drow += kBL; fC = pf[64];
      d = step_planeA(trb, d, fD); *drow = d; drow += kBL; fD = pf[128];
      d = step_planeA(trb, d, fA); *drow = d; drow += kBL; fA = pf[192];
      pf += 256;
    }
    float g0 = pf[0], g1 = pf[64];  // t=4094, 4095
    d = step_planeA(trb, d, fB); *drow = d; drow += kBL;
    d = step_planeA(trb, d, fC); *drow = d; drow += kBL;
    d = step_planeA(trb, d, fD); *drow = d; drow += kBL;
    d = step_planeA(trb, d, fA); *drow = d; drow += kBL;
    d = step_planeA(trb, d, g0); *drow = d; drow += kBL;
    d = step_planeA(trb, d, g1); *drow = d;
    return;
  }
#endif
  if (mode == 2) {
    for (int it = 0; it < 1022; ++it) {
      d = step_planeB(trb, d, fB); *drow = d; drow += kBL; fB = pf[0];
      d = step_planeB(trb, d, fC); *drow = d; drow += kBL; fC = pf[64];
      d = step_planeB(trb, d, fD); *drow = d; drow += kBL; fD = pf[128];
      d = step_planeB(trb, d, fA); *drow = d; drow += kBL; fA = pf[192];
      pf += 256;
    }
    float g0 = pf[0], g1 = pf[64];
    d = step_planeB(trb, d, fB); *drow = d; drow += kBL;
    d = step_planeB(trb, d, fC); *drow = d; drow += kBL;
    d = step_planeB(trb, d, fD); *drow = d; drow += kBL;
    d = step_planeB(trb, d, fA); *drow = d; drow += kBL;
    d = step_planeB(trb, d, g0); *drow = d; drow += kBL;
    d = step_planeB(trb, d, g1); *drow = d;
    return;
  }
  {
    for (int it = 0; it < 1022; ++it) {
      d = step_lds(tr2, dl, dl4, i, d, fB); *drow = d; drow += kBL; fB = pf[0];
      d = step_lds(tr2, dl, dl4, i, d, fC); *drow = d; drow += kBL; fC = pf[64];
      d = step_lds(tr2, dl, dl4, i, d, fD); *drow = d; drow += kBL; fD = pf[128];
      d = step_lds(tr2, dl, dl4, i, d, fA); *drow = d; drow += kBL; fA = pf[192];
      pf += 256;
    }
    float g0 = pf[0], g1 = pf[64];
    d = step_lds(tr2, dl, dl4, i, d, fB); *drow = d; drow += kBL;
    d = step_lds(tr2, dl, dl4, i, d, fC); *drow = d; drow += kBL;
    d = step_lds(tr2, dl, dl4, i, d, fD); *drow = d; drow += kBL;
    d = step_lds(tr2, dl, dl4, i, d, fA); *drow = d; drow += kBL;
    d = step_lds(tr2, dl, dl4, i, d, g0); *drow = d; drow += kBL;
    d = step_lds(tr2, dl, dl4, i, d, g1); *drow = d;
  }
}

// ---------------- K2: recompute backpointers from stored delta --------------
// row r = t*128 + b; delta layout [T][B][L] makes row base = delta + r*64.
__global__ __launch_bounds__(256) void psi_from_delta(const float* __restrict__ delta,
                                                      const float* __restrict__ trans,
                                                      unsigned char* __restrict__ psi) {
  const int lane = threadIdx.x & 63;
  const int w = __builtin_amdgcn_readfirstlane(blockIdx.x * 4 + (threadIdx.x >> 6));
  float tr[kL];
#pragma unroll
  for (int k = 0; k < kL; k += 4) {
    float4 v = *reinterpret_cast<const float4*>(trans + lane * kL + k);
    tr[k] = v.x; tr[k + 1] = v.y; tr[k + 2] = v.z; tr[k + 3] = v.w;
  }
  const int r0 = w * 8;  // 8 rows per wave; grid sized exactly
  for (int rr = 0; rr < 8; ++rr) {
    const int r = r0 + rr;
    const float4* row4 = reinterpret_cast<const float4*>(delta + (size_t)r * kL);
    float bA = -INFINITY, bBv = -INFINITY;
    int iA = 0, iB = 32;
#pragma unroll
    for (int q = 0; q < 8; ++q) {
      float4 dv = row4[q];
      float c; bool g;
      c = tr[4 * q + 0] + dv.x; g = c > bA; bA = g ? c : bA; iA = g ? 4 * q + 0 : iA;
      c = tr[4 * q + 1] + dv.y; g = c > bA; bA = g ? c : bA; iA = g ? 4 * q + 1 : iA;
      c = tr[4 * q + 2] + dv.z; g = c > bA; bA = g ? c : bA; iA = g ? 4 * q + 2 : iA;
      c = tr[4 * q + 3] + dv.w; g = c > bA; bA = g ? c : bA; iA = g ? 4 * q + 3 : iA;
    }
#pragma unroll
    for (int q = 8; q < 16; ++q) {
      float4 dv = row4[q];
      float c; bool g;
      c = tr[4 * q + 0] + dv.x; g = c > bBv; bBv = g ? c : bBv; iB = g ? 4 * q + 0 : iB;
      c = tr[4 * q + 1] + dv.y; g = c > bBv; bBv = g ? c : bBv; iB = g ? 4 * q + 1 : iB;
      c = tr[4 * q + 2] + dv.z; g = c > bBv; bBv = g ? c : bBv; iB = g ? 4 * q + 2 : iB;
      c = tr[4 * q + 3] + dv.w; g = c > bBv; bBv = g ? c : bBv; iB = g ? 4 * q + 3 : iB;
    }
    bool gm = bBv > bA;  // tie -> lower half (first occurrence)
    psi[(size_t)r * kL + lane] = (unsigned char)(gm ? iB : iA);
  }
}

// ---------------- K3: segment composition (in-place psi -> M) ----------------
__global__ __launch_bounds__(256) void seg_compose(unsigned char* psiM,
                                                   unsigned char* __restrict__ C) {
  const int lane = threadIdx.x & 63;
  const int w = blockIdx.x * 4 + (threadIdx.x >> 6);
  const int s = w >> 7;
  const int b = w & 127;
  const int tstart = s * kSegLen;
  const int tend = (tstart + kSegLen < kT) ? tstart + kSegLen : kT - 1;  // last seg: 4095
  const size_t stride = (size_t)kB * kL;
  size_t off = ((size_t)(tend - 1) * kB + b) * kL + lane;
  int m = lane;
  int v = psiM[off];
  for (int t = tend - 1; t > tstart; --t) {
    int vn = psiM[off - stride];          // prefetch next row
    m = __shfl(v, m, 64);                 // m = psi_row[m]
    psiM[off] = (unsigned char)m;         // M[t][b][e] = path[t] | hyp e
    v = vn;
    off -= stride;
  }
  m = __shfl(v, m, 64);
  psiM[off] = (unsigned char)m;
  C[((size_t)s * kB + b) * kL + lane] = (unsigned char)m;  // composed map
}

// ---------------- K4: score, last label, boundary-label scan ----------------
__global__ __launch_bounds__(64) void score_scan(const float* __restrict__ dfin,
                                                 const unsigned char* __restrict__ C,
                                                 int* __restrict__ E,
                                                 float* __restrict__ out) {
  const int b = blockIdx.x;
  const int i = threadIdx.x;
  float d = dfin[(size_t)b * kL + i];
  float m = d;
#pragma unroll
  for (int off = 32; off; off >>= 1) m = fmaxf(m, __shfl_xor(m, off, 64));
  unsigned long long msk = __ballot(d == m);
  int ll = __ffsll(msk) - 1;  // first (lowest) argmax lane
  if (i == 0) {
    out[b] = m;
    out[kB + (size_t)b * kT + (kT - 1)] = (float)ll;
    int lbl = ll;
    for (int s = kSeg - 1; s >= 0; --s) {
      E[s * kB + b] = lbl;                              // label at t_end(s)
      lbl = C[((size_t)s * kB + b) * kL + lbl];         // -> label at t_start(s)
    }
  }
}

// ---------------- K5: parallel path gather ----------------
__global__ __launch_bounds__(256) void path_fill(const unsigned char* __restrict__ M,
                                                 const int* __restrict__ E,
                                                 float* __restrict__ out) {
  const int n = blockIdx.x * 256 + threadIdx.x;  // n = b*4096 + t
  const int b = n >> 12;
  const int t = n & (kT - 1);
  if (t == kT - 1) return;  // written by score_scan
  const int e = E[(t >> 6) * kB + b];
  const unsigned char lab = M[((size_t)t * kB + b) * kL + e];
  out[kB + (size_t)b * kT + t] = (float)lab;
}

extern "C" void kernel_launch(void* const* d_in, const int* in_sizes, int n_in,
                              void* d_out, int out_size, void* d_ws, size_t ws_size,
                              hipStream_t stream) {
  const float* feats = (const float*)d_in[0];
  const float* trans = (const float*)d_in[1];
  float* out = (float*)d_out;
  char* ws = (char*)d_ws;

  const size_t deltaB = (size_t)kT * kB * kL * 4;   // 134,217,728
  const size_t psiB   = (size_t)kT * kB * kL;       //  33,554,432
  const size_t CBy    = (size_t)kSeg * kB * kL;     //     524,288

  float* delta = (float*)ws;
  unsigned char* psi = (unsigned char*)(ws + deltaB);
  unsigned char* C = (unsigned char*)(ws + deltaB + psiB);
  int* E = (int*)(ws + deltaB + psiB + CBy);
  hipLaunchKernelGGL(fwd_delta, dim3(kB), dim3(64), 0, stream, feats, trans, delta);
  hipLaunchKernelGGL(psi_from_delta, dim3(16380), dim3(256), 0, stream, delta, trans, psi);
  hipLaunchKernelGGL(seg_compose, dim3(2048), dim3(256), 0, stream, psi, C);
  hipLaunchKernelGGL(score_scan, dim3(kB), dim3(64), 0, stream,
                     delta + (size_t)(kT - 1) * kB * kL, C, E, out);
  hipLaunchKernelGGL(path_fill, dim3(2048), dim3(256), 0, stream, psi, E, out);
}